// Round 17
// baseline (83.712 us; speedup 1.0000x reference)
//
#include <hip/hip_runtime.h>

// ---------------------------------------------------------------------------
// KAN forward as one bf16 MFMA GEMM:
//   y[n,o] = sum_i ( silu(x[n,i])*scale_base[o,i]
//                  + sum_b basis_b(x[n,i]) * scale_sp[o,i]*coef[o,i,b] ) + bias[o]
// A[n, i*8+s], W[o, i*8+s]: s=0 -> (silu, scale_base); s=1..6 -> (basis, sp*coef);
// s=7 -> zero pad.  K = 512*8 = 4096.
// Round 17: r16's asm-pinned pipeline + r15's AF-prefetch-one-kt-ahead.
// Depth-4 LDS act ring (acts produced 2 kt ahead); AF(kt+1) ds_reads issue at
// the top of STEP(kt) and are consumed only after the barrier -> the MFMA
// cluster covers their latency; MFMA(kt) runs with NO lgkm wait (AFc drained
// at last step's lgkmcnt(0), Bc guaranteed by vmcnt(9)). All loop memory ops
// are volatile asm so the compiler cannot collapse the prefetch distance
// (r15 lesson: VGPR=124 proved it had).
// ---------------------------------------------------------------------------

typedef short        bf16x8 __attribute__((ext_vector_type(8)));
typedef float        f32x4  __attribute__((ext_vector_type(4)));
typedef unsigned int u32x4  __attribute__((ext_vector_type(4)));

#define NROWS 16384
#define DIN   512
#define DOUT  512
#define BM    64
#define BN    512
#define NKT   64              // K-steps; each covers 8 input features

__device__ __forceinline__ unsigned short f2bf(float f) {
    unsigned int u = __float_as_uint(f);
    u += 0x7fffu + ((u >> 16) & 1u);          // round-to-nearest-even
    return (unsigned short)(u >> 16);
}

// ---------------------------------------------------------------------------
// Register-built activation: 8 bf16 slots [silu, basis0..5, pad] for one x,
// returned as u32x4 (caller stores with one ds_write_b128).
// ---------------------------------------------------------------------------
__device__ __forceinline__ u32x4 kan_act(float xv) {
    float S  = __builtin_fmaf(xv, 1.5f, 4.5f);
    float jf = floorf(S);
    float t  = S - jf;
    int   j  = (int)jf;
    float t2 = t * t;
    float t3 = t2 * t;
    float omt  = 1.0f - t;
    float omt2 = omt * omt;
    float n0 = omt2 * omt * (1.0f / 6.0f);                    // (1-t)^3/6
    float n1 = __builtin_fmaf(t3, 0.5f, -t2) + (2.0f / 3.0f); // (3t^3-6t^2+4)/6
    float u  = (t + t2) - t3;
    float n2 = __builtin_fmaf(u, 0.5f, 1.0f / 6.0f);          // (-3t^3+3t^2+3t+1)/6
    float n3 = t3 * (1.0f / 6.0f);                            // t^3/6
    float e  = __expf(-xv);
    float si = xv * __builtin_amdgcn_rcpf(1.0f + e);          // silu

    unsigned P01, P23, WS;
    asm("v_cvt_pk_bf16_f32 %0, %1, %2" : "=v"(P01) : "v"(n0), "v"(n1));
    asm("v_cvt_pk_bf16_f32 %0, %1, %2" : "=v"(P23) : "v"(n2), "v"(n3));
    asm("v_cvt_pk_bf16_f32 %0, %1, %2" : "=v"(WS)  : "v"(si), "v"(0.0f));
    unsigned U = P01 << 16;                      // (0 , n0)
    unsigned V = (P01 >> 16) | (P23 << 16);      // (n1, n2)
    unsigned Z = P23 >> 16;                      // (n3, 0 )
    bool odd = (j & 1) != 0;
    unsigned c0 = odd ? U : P01;
    unsigned c1 = odd ? V : P23;
    unsigned c2 = odd ? Z : 0u;
    int b = (j - 2) >> 1;                        // arithmetic shift (floor)
    u32x4 w;
    w[0] = (b == 0) ? c0 : (b == -1) ? c1 : (b == -2) ? c2 : 0u;
    w[1] = (b == 1) ? c0 : (b ==  0) ? c1 : (b == -1) ? c2 : 0u;
    w[2] = (b == 2) ? c0 : (b ==  1) ? c1 : (b ==  0) ? c2 : 0u;
    w[3] = (b == 3) ? c0 : (b ==  2) ? c1 : (b ==  1) ? c2 : 0u;
    w[0] = (w[0] & 0xFFFF0000u) | (WS & 0xFFFFu);   // silu -> slot 0
    return w;
}

// ---------------------------------------------------------------------------
// Prep: pack W as bf16 16B slot-groups, coalesced for the GEMM:
//   byte = ((kt*2 + ks)*512 + o)*64 + fg*16      (i = kt*8 + ks*4 + fg)
// ---------------------------------------------------------------------------
__global__ __launch_bounds__(256) void kan_prep(
    const float* __restrict__ coef, const float* __restrict__ scale_base,
    const float* __restrict__ scale_sp, unsigned short* __restrict__ wt)
{
    int t = blockIdx.x * 256 + threadIdx.x;   // t = o*512 + i
    int o = t >> 9;
    int i = t & 511;
    float sb = scale_base[t];
    float sp = scale_sp[t];
    const float* cp = coef + (size_t)t * 6;
    bf16x8 w;
    w[0] = (short)f2bf(sb);
#pragma unroll
    for (int b = 0; b < 6; ++b) w[1 + b] = (short)f2bf(sp * cp[b]);
    w[7] = 0;
    int kt = i >> 3, s = i & 7, ks = s >> 2, fg = s & 3;
    size_t off = ((size_t)((kt * 2 + ks) * 512 + o)) * 64 + fg * 16;
    *(bf16x8*)((char*)wt + off) = w;
}

// ---------------------------------------------------------------------------
// Fused GEMM: BM=64 x BN=512, 512 threads (8 waves, wave tile 64x64 at
// col = wid*64), asm-pinned pipeline with AF-prefetch-one-ahead.
// ---------------------------------------------------------------------------
__global__ __launch_bounds__(512, 2) void kan_gemm(
    const float* __restrict__ x, const unsigned short* __restrict__ wt,
    const float* __restrict__ bias, float* __restrict__ y)
{
    __shared__ char As[4][BM * 128];   // depth-4 ring, 32 KB, swizzled rows

    const int tid  = threadIdx.x;
    const int lane = tid & 63;
    const int wid  = tid >> 6;        // 0..7 (col slice)

    // bijective XCD-aware swizzle: 256 wgs, 8 XCDs, contiguous 32-chunk each.
    int bid = blockIdx.x;
    int mt  = (bid & 7) * 32 + (bid >> 3);    // 0..255
    const int row0 = mt * BM;

    // A staging: thread -> (row ar, feature ap); ONE act per thread per kt
    const int ar = tid >> 3;          // 0..63
    const int ap = tid & 7;           // 0..7
    const float* xp = x + (size_t)(row0 + ar) * DIN + ap;
    const int as_sw = (ar & 7) << 4;
    const int c0 = ap << 4;

    const int fr = lane & 15;         // fragment row/col
    const int fg = lane >> 4;         // k-group 0..3

    // LDS byte offset of As base
    const unsigned asb =
        (unsigned)(unsigned long long)(__attribute__((address_space(3))) char*)&As[0][0];

    // B-frag per-thread base pointers: frag (ks, n2) at iter kt reads 16B at
    //   pB[n2] + kt*65536 + ks*32768
    const char* pB[4];
#pragma unroll
    for (int n2 = 0; n2 < 4; ++n2)
        pB[n2] = (const char*)wt + (size_t)((wid * 64 + n2 * 16 + fr) * 64 + fg * 16);

    f32x4 acc[4][4];
#pragma unroll
    for (int m2 = 0; m2 < 4; ++m2)
#pragma unroll
        for (int n2 = 0; n2 < 4; ++n2) {
            f32x4 z = {0.f, 0.f, 0.f, 0.f};
            acc[m2][n2] = z;
        }

    bf16x8 Ba[8], Bb[8];      // B dbuf
    bf16x8 AFa[8], AFb[8];    // A-frag dbuf
    float  xA, xB;

    // ---------------- prologue ----------------
    // acts(0) -> slot0, acts(1) -> slot1 (plain x loads; one-time waits)
    {
        u32x4 w0 = kan_act(xp[0]);
        unsigned o0 = asb + ar * 128 + (c0 ^ as_sw);
        asm volatile("ds_write_b128 %0, %1" :: "v"(o0), "v"(w0));
        u32x4 w1 = kan_act(xp[8]);
        asm volatile("ds_write_b128 %0, %1" :: "v"(o0 + 8192), "v"(w1));
    }
    // B(0) -> Ba + x[16] (act(2), consumed in STEP(0)) : 9 VMEM in flight
#pragma unroll
    for (int q = 0; q < 8; ++q) {
        int n2_ = q & 3, ks_ = q >> 2;
        const void* a_ = pB[n2_] + ks_ * 32768;
        asm volatile("global_load_dwordx4 %0, %1, off" : "=&v"(Ba[q]) : "v"(a_));
    }
    asm volatile("global_load_dword %0, %1, off"
                 : "=&v"(xA) : "v"((const void*)(xp + 16)));
    asm volatile("s_waitcnt lgkmcnt(0)");
    __builtin_amdgcn_s_barrier();
    // AF(0) from slot0; drain before loop (one-time exposed LDS read)
#pragma unroll
    for (int q = 0; q < 8; ++q) {
        int ks_ = q >> 2, m2_ = q & 3;
        int rr_ = m2_ * 16 + fr;
        unsigned off_ = asb + rr_ * 128
            + ((unsigned)(ks_ * 64 + fg * 16) ^ (unsigned)((rr_ & 7) << 4));
        asm volatile("ds_read_b128 %0, %1" : "=&v"(AFa[q]) : "v"(off_));
    }
    asm volatile("s_waitcnt lgkmcnt(0)");

// STEP(kt). Entry invariant: 9 VMEM outstanding = [B(kt) x8, x for act(kt+2)];
// AFc holds frags(kt) (drained); slot (kt+1) published by last barrier.
// 1. issue B(kt+1)x8 + x(kt+3) [9 VMEM]     2. issue AF(kt+1) ds_reads x8
// 3. vmcnt(9): B(kt)+xcur landed            4. act(kt+2) -> slot[(kt+2)&3]
// 5. MFMA(AFc, Bc) - register-only          6. lgkmcnt(0) + barrier
#define STEP(ktv, Bc, Bn, AFc, AFn, xcur, xnext)                              \
    {                                                                         \
        const bool hn_ = (ktv) + 1 < NKT;                                     \
        if (hn_) {                                                            \
            size_t ko_ = (size_t)((ktv) + 1) * 65536;                         \
            _Pragma("unroll")                                                 \
            for (int q = 0; q < 8; ++q) {                                     \
                int n2_ = q & 3, ks_ = q >> 2;                                \
                const void* a_ = pB[n2_] + ko_ + ks_ * 32768;                 \
                asm volatile("global_load_dwordx4 %0, %1, off"                \
                             : "=&v"(Bn[q]) : "v"(a_));                       \
            }                                                                 \
            int xo_ = ((ktv) + 3 < NKT) ? ((ktv) + 3) * 8 : 0;                \
            asm volatile("global_load_dword %0, %1, off"                      \
                         : "=&v"(xnext) : "v"((const void*)(xp + xo_)));      \
            const unsigned abn_ = asb + (((ktv) + 1) & 3) * 8192;             \
            _Pragma("unroll")                                                 \
            for (int q = 0; q < 8; ++q) {                                     \
                int ks_ = q >> 2, m2_ = q & 3;                                \
                int rr_ = m2_ * 16 + fr;                                      \
                unsigned off_ = abn_ + rr_ * 128                              \
                    + ((unsigned)(ks_ * 64 + fg * 16)                         \
                       ^ (unsigned)((rr_ & 7) << 4));                         \
                asm volatile("ds_read_b128 %0, %1" : "=&v"(AFn[q]) : "v"(off_)); \
            }                                                                 \
            asm volatile("s_waitcnt vmcnt(9)");                               \
        } else {                                                              \
            asm volatile("s_waitcnt vmcnt(0)");                               \
        }                                                                     \
        __builtin_amdgcn_sched_barrier(0);                                    \
        if ((ktv) + 2 < NKT) {                                                \
            u32x4 w_ = kan_act(xcur);                                         \
            unsigned wo_ = asb + (((ktv) + 2) & 3) * 8192 + ar * 128          \
                           + (c0 ^ as_sw);                                    \
            asm volatile("ds_write_b128 %0, %1" :: "v"(wo_), "v"(w_));        \
        }                                                                     \
        __builtin_amdgcn_sched_barrier(0);                                    \
        _Pragma("unroll")                                                     \
        for (int ks_ = 0; ks_ < 2; ++ks_)                                     \
            _Pragma("unroll")                                                 \
            for (int m2_ = 0; m2_ < 4; ++m2_)                                 \
                _Pragma("unroll")                                             \
                for (int n2_ = 0; n2_ < 4; ++n2_)                             \
                    acc[m2_][n2_] = __builtin_amdgcn_mfma_f32_16x16x32_bf16(  \
                        AFc[ks_ * 4 + m2_], Bc[ks_ * 4 + n2_], acc[m2_][n2_], \
                        0, 0, 0);                                             \
        if (hn_) {                                                            \
            asm volatile("s_waitcnt lgkmcnt(0)");                             \
            __builtin_amdgcn_s_barrier();                                     \
        }                                                                     \
    }

    for (int kt = 0; kt < NKT; kt += 2) {
        STEP(kt,     Ba, Bb, AFa, AFb, xA, xB);
        STEP(kt + 1, Bb, Ba, AFb, AFa, xB, xA);
    }

    // ---- epilogue: C/D layout col = lane&15, row = (lane>>4)*4 + reg
    const int orow0 = row0 + fg * 4;
    const int ocol0 = wid * 64 + fr;
#pragma unroll
    for (int n2 = 0; n2 < 4; ++n2) {
        float bv = bias[ocol0 + n2 * 16];
#pragma unroll
        for (int m2 = 0; m2 < 4; ++m2) {
#pragma unroll
            for (int r = 0; r < 4; ++r) {
                y[(size_t)(orow0 + m2 * 16 + r) * DOUT + (ocol0 + n2 * 16)]
                    = acc[m2][n2][r] + bv;
            }
        }
    }
#undef STEP
}

extern "C" void kernel_launch(void* const* d_in, const int* in_sizes, int n_in,
                              void* d_out, int out_size, void* d_ws, size_t ws_size,
                              hipStream_t stream)
{
    const float* x          = (const float*)d_in[0];
    const float* coef       = (const float*)d_in[1];
    const float* scale_base = (const float*)d_in[2];
    const float* scale_sp   = (const float*)d_in[3];
    const float* bias       = (const float*)d_in[4];
    unsigned short* wt = (unsigned short*)d_ws;   // 4 MB packed wt[kt][ks][o][fg]
    float* y = (float*)d_out;

    kan_prep<<<1024, 256, 0, stream>>>(coef, scale_base, scale_sp, wt);
    kan_gemm<<<256, 512, 0, stream>>>(x, wt, bias, y);
}

// Round 18
// 78.320 us; speedup vs baseline: 1.0689x; 1.0689x over previous
//
#include <hip/hip_runtime.h>

// ---------------------------------------------------------------------------
// KAN forward as one bf16 MFMA GEMM:
//   y[n,o] = sum_i ( silu(x[n,i])*scale_base[o,i]
//                  + sum_b basis_b(x[n,i]) * scale_sp[o,i]*coef[o,i,b] ) + bias[o]
// A[n, i*8+s], W[o, i*8+s]: s=0 -> (silu, scale_base); s=1..6 -> (basis, sp*coef);
// s=7 -> zero pad.  K = 512*8 = 4096.
// Round 18: r16 (best, 82.4us) with addressing off the VALU and split waits:
// - B/x loads via SGPR-base saddr form (voff VGPRs computed once; per-kt
//   base step is SALU), AF/act LDS ops via fixed base + offset: immediates.
// - wait ladder: vmcnt(14)+lgkmcnt(4) -> MFMA ks0 -> vmcnt(9) -> act+write ->
//   lgkmcnt(1) -> MFMA ks1 -> lgkmcnt(0)+barrier.
// ---------------------------------------------------------------------------

typedef short        bf16x8 __attribute__((ext_vector_type(8)));
typedef float        f32x4  __attribute__((ext_vector_type(4)));
typedef unsigned int u32x4  __attribute__((ext_vector_type(4)));

#define NROWS 16384
#define DIN   512
#define DOUT  512
#define BM    64
#define BN    512
#define NKT   64              // K-steps; each covers 8 input features

__device__ __forceinline__ unsigned short f2bf(float f) {
    unsigned int u = __float_as_uint(f);
    u += 0x7fffu + ((u >> 16) & 1u);          // round-to-nearest-even
    return (unsigned short)(u >> 16);
}

// ---------------------------------------------------------------------------
// Register-built activation: 8 bf16 slots [silu, basis0..5, pad] for one x.
// ---------------------------------------------------------------------------
__device__ __forceinline__ u32x4 kan_act(float xv) {
    float S  = __builtin_fmaf(xv, 1.5f, 4.5f);
    float jf = floorf(S);
    float t  = S - jf;
    int   j  = (int)jf;
    float t2 = t * t;
    float t3 = t2 * t;
    float omt  = 1.0f - t;
    float omt2 = omt * omt;
    float n0 = omt2 * omt * (1.0f / 6.0f);                    // (1-t)^3/6
    float n1 = __builtin_fmaf(t3, 0.5f, -t2) + (2.0f / 3.0f); // (3t^3-6t^2+4)/6
    float u  = (t + t2) - t3;
    float n2 = __builtin_fmaf(u, 0.5f, 1.0f / 6.0f);          // (-3t^3+3t^2+3t+1)/6
    float n3 = t3 * (1.0f / 6.0f);                            // t^3/6
    float e  = __expf(-xv);
    float si = xv * __builtin_amdgcn_rcpf(1.0f + e);          // silu

    unsigned P01, P23, WS;
    asm("v_cvt_pk_bf16_f32 %0, %1, %2" : "=v"(P01) : "v"(n0), "v"(n1));
    asm("v_cvt_pk_bf16_f32 %0, %1, %2" : "=v"(P23) : "v"(n2), "v"(n3));
    asm("v_cvt_pk_bf16_f32 %0, %1, %2" : "=v"(WS)  : "v"(si), "v"(0.0f));
    unsigned U = P01 << 16;                      // (0 , n0)
    unsigned V = (P01 >> 16) | (P23 << 16);      // (n1, n2)
    unsigned Z = P23 >> 16;                      // (n3, 0 )
    bool odd = (j & 1) != 0;
    unsigned c0 = odd ? U : P01;
    unsigned c1 = odd ? V : P23;
    unsigned c2 = odd ? Z : 0u;
    int b = (j - 2) >> 1;                        // arithmetic shift (floor)
    u32x4 w;
    w[0] = (b == 0) ? c0 : (b == -1) ? c1 : (b == -2) ? c2 : 0u;
    w[1] = (b == 1) ? c0 : (b ==  0) ? c1 : (b == -1) ? c2 : 0u;
    w[2] = (b == 2) ? c0 : (b ==  1) ? c1 : (b ==  0) ? c2 : 0u;
    w[3] = (b == 3) ? c0 : (b ==  2) ? c1 : (b ==  1) ? c2 : 0u;
    w[0] = (w[0] & 0xFFFF0000u) | (WS & 0xFFFFu);   // silu -> slot 0
    return w;
}

// ---------------------------------------------------------------------------
// Prep: pack W as bf16 16B slot-groups, coalesced for the GEMM:
//   byte = ((kt*2 + ks)*512 + o)*64 + fg*16      (i = kt*8 + ks*4 + fg)
// ---------------------------------------------------------------------------
__global__ __launch_bounds__(256) void kan_prep(
    const float* __restrict__ coef, const float* __restrict__ scale_base,
    const float* __restrict__ scale_sp, unsigned short* __restrict__ wt)
{
    int t = blockIdx.x * 256 + threadIdx.x;   // t = o*512 + i
    int o = t >> 9;
    int i = t & 511;
    float sb = scale_base[t];
    float sp = scale_sp[t];
    const float* cp = coef + (size_t)t * 6;
    bf16x8 w;
    w[0] = (short)f2bf(sb);
#pragma unroll
    for (int b = 0; b < 6; ++b) w[1 + b] = (short)f2bf(sp * cp[b]);
    w[7] = 0;
    int kt = i >> 3, s = i & 7, ks = s >> 2, fg = s & 3;
    size_t off = ((size_t)((kt * 2 + ks) * 512 + o)) * 64 + fg * 16;
    *(bf16x8*)((char*)wt + off) = w;
}

// ---------------------------------------------------------------------------
// Fused GEMM: BM=64 x BN=512, 512 threads (8 waves, wave tile 64x64 at
// col = wid*64), asm-pinned pipeline, SGPR-base addressing, split waits.
// ---------------------------------------------------------------------------
__global__ __launch_bounds__(512, 2) void kan_gemm(
    const float* __restrict__ x, const unsigned short* __restrict__ wt,
    const float* __restrict__ bias, float* __restrict__ y)
{
    __shared__ char As[2][BM * 128];   // 2 x 8 KB ring, swizzled rows

    const int tid  = threadIdx.x;
    const int lane = tid & 63;
    const int wid  = tid >> 6;        // 0..7 (col slice)

    // bijective XCD-aware swizzle: 256 wgs, 8 XCDs, contiguous 32-chunk each.
    int bid = blockIdx.x;
    int mt  = (bid & 7) * 32 + (bid >> 3);    // 0..255
    const int row0 = mt * BM;

    // A staging: thread -> (row ar, feature ap); ONE act per thread per kt
    const int ar = tid >> 3;          // 0..63
    const int ap = tid & 7;           // 0..7
    const int as_sw = (ar & 7) << 4;
    const int c0 = ap << 4;

    const int fr = lane & 15;         // fragment row/col
    const int fg = lane >> 4;         // k-group 0..3

    // LDS byte offset of As base
    const unsigned asb =
        (unsigned)(unsigned long long)(__attribute__((address_space(3))) char*)&As[0][0];

    // ---- per-thread invariant offsets (computed once) ----
    unsigned voffB[8];                // B-frag 32-bit voffsets (saddr form)
#pragma unroll
    for (int q = 0; q < 8; ++q) {
        int n2_ = q & 3, ks_ = q >> 2;
        voffB[q] = (unsigned)((wid * 64 + n2_ * 16 + fr) * 64 + fg * 16
                              + ks_ * 32768);
    }
    unsigned afoff[8];                // A-frag LDS base offsets (slot 0)
#pragma unroll
    for (int q = 0; q < 8; ++q) {
        int ks_ = q >> 2, m2_ = q & 3;
        int rr_ = m2_ * 16 + fr;
        afoff[q] = asb + (unsigned)(rr_ * 128)
                 + (((unsigned)(ks_ * 64 + fg * 16)) ^ ((unsigned)((rr_ & 7) << 4)));
    }
    const unsigned awoff = asb + (unsigned)(ar * 128) + (unsigned)(c0 ^ as_sw);
    const unsigned vxoff = (unsigned)((ar * DIN + ap) * 4);
    const char* xrow = (const char*)(x + (size_t)row0 * DIN);   // + kt*32 (SALU)

    f32x4 acc[4][4];
#pragma unroll
    for (int m2 = 0; m2 < 4; ++m2)
#pragma unroll
        for (int n2 = 0; n2 < 4; ++n2) {
            f32x4 z = {0.f, 0.f, 0.f, 0.f};
            acc[m2][n2] = z;
        }

    bf16x8 Ba[8], Bb[8];
    float  xA, xB;

    // ---------------- prologue ----------------
    // act(0) -> slot 0
    {
        u32x4 w0 = kan_act(*(const float*)(xrow + vxoff));
        asm volatile("ds_write_b128 %0, %1" :: "v"(awoff), "v"(w0));
    }
    // B(0) -> Ba + x(1): 9 VMEM in flight into STEP(0)
#pragma unroll
    for (int q = 0; q < 8; ++q)
        asm volatile("global_load_dwordx4 %0, %1, %2"
                     : "=&v"(Ba[q]) : "v"(voffB[q]), "s"((const void*)wt));
    asm volatile("global_load_dword %0, %1, %2"
                 : "=&v"(xA) : "v"(vxoff), "s"((const void*)(xrow + 1 * 32)));
    asm volatile("s_waitcnt lgkmcnt(0)");
    __builtin_amdgcn_s_barrier();

// STEP(kt). Entry: 9 VMEM outstanding = [B(kt) x8, x(kt+1)]; slot CUR holds
// acts(kt) (published by last barrier).
//  AF ds_reads (slot CUR)  ->  issue B(kt+1) x8 + x(kt+2)  [18 VMEM, 8 LDS]
//  vmcnt(14): B(kt) ks0 landed; lgkmcnt(4): AF ks0 done  ->  16 MFMA ks0
//  vmcnt(9): B(kt) ks1 + x(kt+1) landed  ->  act(kt+1) -> slot CUR^1
//  lgkmcnt(1): AF ks1 done (write pending)  ->  16 MFMA ks1
//  lgkmcnt(0) + barrier (publish slot CUR^1)
#define STEP(ktv, CUR, Bc, Bn, xcur, xnext)                                   \
    {                                                                         \
        const bool hn_ = (ktv) + 1 < NKT;                                     \
        bf16x8 AF[8];                                                         \
        _Pragma("unroll")                                                     \
        for (int q = 0; q < 8; ++q)                                           \
            asm volatile("ds_read_b128 %0, %1 offset:%c2"                     \
                         : "=&v"(AF[q]) : "v"(afoff[q]), "i"((CUR) * 8192));  \
        if (hn_) {                                                            \
            const void* wb1_ = (const char*)wt + (size_t)((ktv) + 1) * 65536; \
            _Pragma("unroll")                                                 \
            for (int q = 0; q < 8; ++q)                                       \
                asm volatile("global_load_dwordx4 %0, %1, %2"                 \
                             : "=&v"(Bn[q]) : "v"(voffB[q]), "s"(wb1_));      \
            int xk_ = ((ktv) + 2 < NKT) ? ((ktv) + 2) : 0;                    \
            asm volatile("global_load_dword %0, %1, %2"                       \
                         : "=&v"(xnext)                                       \
                         : "v"(vxoff), "s"((const void*)(xrow + xk_ * 32)));  \
            asm volatile("s_waitcnt vmcnt(14) lgkmcnt(4)");                   \
        } else {                                                              \
            asm volatile("s_waitcnt vmcnt(0) lgkmcnt(0)");                    \
        }                                                                     \
        __builtin_amdgcn_sched_barrier(0);                                    \
        _Pragma("unroll")                                                     \
        for (int m2_ = 0; m2_ < 4; ++m2_)                                     \
            _Pragma("unroll")                                                 \
            for (int n2_ = 0; n2_ < 4; ++n2_)                                 \
                acc[m2_][n2_] = __builtin_amdgcn_mfma_f32_16x16x32_bf16(      \
                    AF[m2_], Bc[n2_], acc[m2_][n2_], 0, 0, 0);                \
        if (hn_) {                                                            \
            asm volatile("s_waitcnt vmcnt(9)");                               \
            __builtin_amdgcn_sched_barrier(0);                                \
            u32x4 w_ = kan_act(xcur);                                         \
            asm volatile("ds_write_b128 %0, %1 offset:%c2"                    \
                         :: "v"(awoff), "v"(w_), "i"(((CUR) ^ 1) * 8192));    \
            asm volatile("s_waitcnt lgkmcnt(1)");                             \
        }                                                                     \
        __builtin_amdgcn_sched_barrier(0);                                    \
        _Pragma("unroll")                                                     \
        for (int m2_ = 0; m2_ < 4; ++m2_)                                     \
            _Pragma("unroll")                                                 \
            for (int n2_ = 0; n2_ < 4; ++n2_)                                 \
                acc[m2_][n2_] = __builtin_amdgcn_mfma_f32_16x16x32_bf16(      \
                    AF[4 + m2_], Bc[4 + n2_], acc[m2_][n2_], 0, 0, 0);        \
        if (hn_) {                                                            \
            asm volatile("s_waitcnt lgkmcnt(0)");                             \
            __builtin_amdgcn_s_barrier();                                     \
        }                                                                     \
    }

    for (int kt = 0; kt < NKT; kt += 2) {
        STEP(kt,     0, Ba, Bb, xA, xB);
        STEP(kt + 1, 1, Bb, Ba, xB, xA);
    }

    // ---- epilogue: C/D layout col = lane&15, row = (lane>>4)*4 + reg
    const int orow0 = row0 + fg * 4;
    const int ocol0 = wid * 64 + fr;
#pragma unroll
    for (int n2 = 0; n2 < 4; ++n2) {
        float bv = bias[ocol0 + n2 * 16];
#pragma unroll
        for (int m2 = 0; m2 < 4; ++m2) {
#pragma unroll
            for (int r = 0; r < 4; ++r) {
                y[(size_t)(orow0 + m2 * 16 + r) * DOUT + (ocol0 + n2 * 16)]
                    = acc[m2][n2][r] + bv;
            }
        }
    }
#undef STEP
}

extern "C" void kernel_launch(void* const* d_in, const int* in_sizes, int n_in,
                              void* d_out, int out_size, void* d_ws, size_t ws_size,
                              hipStream_t stream)
{
    const float* x          = (const float*)d_in[0];
    const float* coef       = (const float*)d_in[1];
    const float* scale_base = (const float*)d_in[2];
    const float* scale_sp   = (const float*)d_in[3];
    const float* bias       = (const float*)d_in[4];
    unsigned short* wt = (unsigned short*)d_ws;   // 4 MB packed wt[kt][ks][o][fg]
    float* y = (float*)d_out;

    kan_prep<<<1024, 256, 0, stream>>>(coef, scale_base, scale_sp, wt);
    kan_gemm<<<256, 512, 0, stream>>>(x, wt, bias, y);
}